// Round 17
// baseline (175.228 us; speedup 1.0000x reference)
//
#include <hip/hip_runtime.h>
#include <math.h>

typedef float2 cf;
typedef float vf2 __attribute__((ext_vector_type(2)));
typedef __attribute__((ext_vector_type(8))) short bf16x8;
typedef __attribute__((ext_vector_type(4))) float f32x4;

__device__ __forceinline__ cf cmk(float x, float y){ cf r; r.x=x; r.y=y; return r; }

// ---- packed-FP32 complex primitives (VOP3P dual-issue; gfx90a+/gfx950) ----
__device__ __forceinline__ cf cad(cf a, cf b){
  vf2 av, bv, rv;
  av.x = a.x; av.y = a.y; bv.x = b.x; bv.y = b.y;
  asm("v_pk_add_f32 %0, %1, %2" : "=v"(rv) : "v"(av), "v"(bv));
  return cmk(rv.x, rv.y);
}
__device__ __forceinline__ cf csb(cf a, cf b){
  vf2 av, bv, rv;
  av.x = a.x; av.y = a.y; bv.x = b.x; bv.y = b.y;
  asm("v_pk_add_f32 %0, %1, %2 neg_lo:[0,1] neg_hi:[0,1]" : "=v"(rv) : "v"(av), "v"(bv));
  return cmk(rv.x, rv.y);
}
// (a.x*b.x - a.y*b.y, a.x*b.y + a.y*b.x) in 2 packed insts
__device__ __forceinline__ cf cml(cf a, cf b){
  vf2 av, bv, rv;
  av.x = a.x; av.y = a.y; bv.x = b.x; bv.y = b.y;
  asm("v_pk_mul_f32 %0, %1, %2 op_sel:[0,0] op_sel_hi:[0,1]\n\t"
      "v_pk_fma_f32 %0, %1, %2, %0 op_sel:[1,1,0] op_sel_hi:[1,0,1] neg_lo:[1,0,0]"
      : "=&v"(rv) : "v"(av), "v"(bv));
  return cmk(rv.x, rv.y);
}

__device__ __forceinline__ cf cjg(cf a){ return cmk(a.x, -a.y); }
__device__ __forceinline__ cf crcp(cf d){ float r = 1.0f/(d.x*d.x + d.y*d.y); return cmk(d.x*r, -d.y*r); }
__device__ __forceinline__ cf cdv(cf n, cf d){ return cml(n, crcp(d)); }
__device__ __forceinline__ float geluf(float z){ return 0.5f*z*(1.0f + erff(z*0.70710678118654752f)); }

// exp(sign*i*pi*f) via native v_sin/v_cos (input in revolutions)
__device__ __forceinline__ cf twid(float f, float sign){
  float h = f * 0.5f;
  float s = __builtin_amdgcn_sinf(h);
  float c0 = __builtin_amdgcn_cosf(h);
  return cmk(c0, sign * s);
}

__device__ __forceinline__ cf shflx(cf v, int m){
  return cmk(__shfl_xor(v.x, m), __shfl_xor(v.y, m));
}

__device__ __forceinline__ void bfsplit(float v, ushort* h, ushort* l){
  unsigned u = __float_as_uint(v);
  unsigned hr = (u + 0x7FFFu + ((u >> 16) & 1u)) & 0xFFFF0000u;
  *h = (ushort)(hr >> 16);
  float lv = v - __uint_as_float(hr);
  unsigned u2 = __float_as_uint(lv);
  *l = (ushort)((u2 + 0x7FFFu + ((u2 >> 16) & 1u)) >> 16);
}

// radix-4 butterflies on a register quad (element strides 0,S,2S,3S), w1 = twid(j/(2S))
__device__ __forceinline__ void dif4q(cf& q0, cf& q1, cf& q2, cf& q3, cf w1, float sign){
  cf w2 = cml(w1, w1);
  cf a1 = cad(q0, q2);
  cf c1 = cml(csb(q0, q2), w1);
  cf b1 = cad(q1, q3);
  cf d1 = cml(csb(q1, q3), cmk(-sign*w1.y, sign*w1.x));
  q0 = cad(a1, b1);
  q1 = cml(csb(a1, b1), w2);
  q2 = cad(c1, d1);
  q3 = cml(csb(c1, d1), w2);
}
__device__ __forceinline__ void dit4q(cf& q0, cf& q1, cf& q2, cf& q3, cf w1, float sign){
  cf w2 = cml(w1, w1);
  cf t1 = cml(q1, w2);
  cf a1 = cad(q0, t1), b1 = csb(q0, t1);
  cf t2 = cml(q3, w2);
  cf c1 = cad(q2, t2), d1 = csb(q2, t2);
  cf v1 = cml(c1, w1);
  cf v2 = cml(d1, cmk(-sign*w1.y, sign*w1.x));
  q0 = cad(a1, v1);
  q2 = csb(a1, v1);
  q1 = cad(b1, v2);
  q3 = csb(b1, v2);
}
// unit-twiddle specializations (w1 = 1)
__device__ __forceinline__ void dif4q0(cf& q0, cf& q1, cf& q2, cf& q3, float sign){
  cf a1 = cad(q0, q2), c1 = csb(q0, q2);
  cf b1 = cad(q1, q3), d0 = csb(q1, q3);
  cf d1 = cmk(-sign*d0.y, sign*d0.x);
  q0 = cad(a1, b1); q1 = csb(a1, b1);
  q2 = cad(c1, d1); q3 = csb(c1, d1);
}
__device__ __forceinline__ void dit4q0(cf& q0, cf& q1, cf& q2, cf& q3, float sign){
  cf a1 = cad(q0, q1), b1 = csb(q0, q1);
  cf c1 = cad(q2, q3), d0 = csb(q2, q3);
  cf v2 = cmk(-sign*d0.y, sign*d0.x);
  q0 = cad(a1, c1); q2 = csb(a1, c1);
  q1 = cad(b1, v2); q3 = csb(b1, v2);
}

__device__ __forceinline__ int brev12(int x){ return (int)(__brev((unsigned)x) >> 20); }
__device__ __forceinline__ int brev13(int x){ return (int)(__brev((unsigned)x) >> 19); }
// bank-spreading pad: +6 cf per 32-cf block (keeps 16-cf runs contiguous & 16B-aligned;
// M2 lane-start banks tile all 4-aligned positions -> conflict-free b128)
__device__ __forceinline__ int pidx(int n){ return n + 6*(n>>5); }

// ---------------- legacy LDS FFT templates (k_kf only), TP-parameterized ----------------
template<int N, int SSTART, int TP>
__device__ void fft_dif_r4(cf* __restrict__ a, float sign){
  #pragma unroll
  for (int s = SSTART; s >= 1; s >>= 2){
    __syncthreads();
    #pragma unroll
    for (int g = 0; g < (N >> 2) / TP; g++){
      int w = (int)threadIdx.x + g * TP;
      int j = w & (s - 1);
      int base = ((w & ~(s - 1)) << 2) | j;
      cf A0 = a[base], B0 = a[base + s], C0 = a[base + 2*s], D0 = a[base + 3*s];
      cf w1 = twid((float)j / (float)(2 * s), sign);
      cf w2 = cml(w1, w1);
      cf a1 = cad(A0, C0);
      cf c1 = cml(csb(A0, C0), w1);
      cf b1 = cad(B0, D0);
      cf d1 = cml(csb(B0, D0), cmk(-sign * w1.y, sign * w1.x));
      a[base]         = cad(a1, b1);
      a[base + s]     = cml(csb(a1, b1), w2);
      a[base + 2*s]   = cad(c1, d1);
      a[base + 3*s]   = cml(csb(c1, d1), w2);
    }
  }
  if constexpr ((__builtin_ctz(N) & 1) == 1){
    __syncthreads();
    #pragma unroll
    for (int g = 0; g < (N >> 1) / TP; g++){
      int w = (int)threadIdx.x + g * TP;
      int i = w << 1;
      cf u = a[i], v = a[i + 1];
      a[i] = cad(u, v);
      a[i + 1] = csb(u, v);
    }
  }
  __syncthreads();
}

template<int N, int TP>
__device__ void fft_dit_r4(cf* __restrict__ a, float sign){
  if constexpr ((__builtin_ctz(N) & 1) == 1){
    __syncthreads();
    #pragma unroll
    for (int g = 0; g < (N >> 1) / TP; g++){
      int w = (int)threadIdx.x + g * TP;
      int i = w << 1;
      cf u = a[i], v = a[i + 1];
      a[i] = cad(u, v);
      a[i + 1] = csb(u, v);
    }
  }
  constexpr int S0 = ((__builtin_ctz(N) & 1) == 1) ? 2 : 1;
  #pragma unroll
  for (int s = S0; s <= (N >> 2); s <<= 2){
    __syncthreads();
    #pragma unroll
    for (int g = 0; g < (N >> 2) / TP; g++){
      int w = (int)threadIdx.x + g * TP;
      int j = w & (s - 1);
      int base = ((w & ~(s - 1)) << 2) | j;
      cf A0 = a[base], B0 = a[base + s], C0 = a[base + 2*s], D0 = a[base + 3*s];
      cf w1 = twid((float)j / (float)(2 * s), sign);
      cf w2 = cml(w1, w1);
      cf t1 = cml(B0, w2);
      cf a1 = cad(A0, t1), b1 = csb(A0, t1);
      cf t2 = cml(D0, w2);
      cf c1 = cad(C0, t2), d1 = csb(C0, t2);
      cf v1 = cml(c1, w1);
      cf v2 = cml(d1, cmk(-sign * w1.y, sign * w1.x));
      a[base]         = cad(a1, v1);
      a[base + 2*s]   = csb(a1, v1);
      a[base + s]     = cad(b1, v2);
      a[base + 3*s]   = csb(b1, v2);
    }
  }
  __syncthreads();
}

template<int TP>
__device__ void dif8192_pad_stage(cf* __restrict__ a, float sign){
  __syncthreads();
  #pragma unroll
  for (int g = 0; g < 2048 / TP; g++){
    int w = (int)threadIdx.x + g * TP;
    cf A0 = a[w], B0 = a[w + 2048];
    cf w1 = twid((float)w * (1.0f / 4096.0f), sign);
    cf w2 = cml(w1, w1);
    cf c1 = cml(A0, w1);
    cf d1 = cml(B0, cmk(-sign * w1.y, sign * w1.x));
    a[w]        = cad(A0, B0);
    a[w + 2048] = cml(csb(A0, B0), w2);
    a[w + 4096] = cad(c1, d1);
    a[w + 6144] = cml(csb(c1, d1), w2);
  }
}

// ---------------- transpose x (B,L,H)->(B,H,L), fused max|x| ----------------
__global__ __launch_bounds__(256) void k_transpose_x(const float* __restrict__ x,
                                                     float* __restrict__ xT,
                                                     unsigned* __restrict__ xmax){
  __shared__ float tile[64][65];
  __shared__ float red[64][4];
  int b = blockIdx.z;
  int t0 = blockIdx.x * 64;
  int h0 = blockIdx.y * 64;
  int hc = threadIdx.x & 63, tg = threadIdx.x >> 6;
  float pmax = 0.0f;
  #pragma unroll
  for (int q = 0; q < 16; q++){
    int tr = tg + q * 4;
    float v = x[((size_t)(b * 4096 + t0 + tr)) * 256 + h0 + hc];
    tile[tr][hc] = v;
    pmax = fmaxf(pmax, fabsf(v));
  }
  red[hc][tg] = pmax;
  __syncthreads();
  if (threadIdx.x < 64){
    float m = fmaxf(fmaxf(red[threadIdx.x][0], red[threadIdx.x][1]),
                    fmaxf(red[threadIdx.x][2], red[threadIdx.x][3]));
    atomicMax(&xmax[b * 256 + h0 + threadIdx.x], __float_as_uint(m));
  }
  #pragma unroll
  for (int q = 0; q < 16; q++){
    int hr = tg + q * 4;
    xT[((size_t)(b * 256 + h0 + hr)) * 4096 + t0 + hc] = tile[hc][hr];
  }
}

// ---------------- W -> bf16 hi/lo planes + init atomic-max + Cauchy prep tables ----------------
__global__ void k_wsplit(const float* __restrict__ W, ushort* __restrict__ Wh, ushort* __restrict__ Wl,
                         unsigned* __restrict__ xmax, unsigned* __restrict__ ymax,
                         const float* __restrict__ Cr, const float* __restrict__ Ci,
                         const float* __restrict__ Br, const float* __restrict__ Bi,
                         const float* __restrict__ Pr, const float* __restrict__ Pi,
                         cf* __restrict__ CBt, cf* __restrict__ CPt){
  int i = blockIdx.x * 256 + threadIdx.x;
  if (i < 2048){ xmax[i] = 0u; ymax[i] = 0u; }
  if (i < 16384){                       // prep: CBt[n][h] = C[h][n]*B[n], CPt = C*P
    int n = i >> 8, h = i & 255;
    cf cc = cmk(Cr[h * 64 + n], Ci[h * 64 + n]);
    CBt[i] = cml(cc, cmk(Br[n], Bi[n]));
    CPt[i] = cml(cc, cmk(Pr[n], Pi[n]));
  }
  ushort h, l;
  bfsplit(W[i], &h, &l);
  Wh[i] = h; Wl[i] = l;
}

// ---------------- Cauchy (8 l per block, 512 blocks, coalesced, no spill) ----------------
__global__ __launch_bounds__(256, 2) void k_cauchy(
    const float* __restrict__ Lr, const float* __restrict__ Li,
    const float* __restrict__ Pr, const float* __restrict__ Pi,
    const float* __restrict__ Qr, const float* __restrict__ Qi,
    const float* __restrict__ Br, const float* __restrict__ Bi,
    const cf* __restrict__ CBt, const cf* __restrict__ CPt,
    const float* __restrict__ stepp, cf* __restrict__ A)
{
  __shared__ cf sLam[64], sQB[64], sQP[64];
  __shared__ cf sInv[64][8];
  __shared__ cf sWood[8], sC[8], sG[8];
  int tid = threadIdx.x;
  int l0 = blockIdx.x * 8;
  float stepv = fmaxf(stepp[0], 1e-6f);
  if (tid < 64){
    cf lam = cmk(Lr[tid], Li[tid]);
    cf b = cmk(Br[tid], Bi[tid]);
    cf p = cmk(Pr[tid], Pi[tid]);
    cf q = cmk(Qr[tid], Qi[tid]);
    sLam[tid] = lam;
    sQB[tid] = cml(q, b);
    sQP[tid] = cml(q, p);
  }
  __syncthreads();
  if (tid < 8){
    int l = l0 + tid;
    float ang = -6.2831855f * ((float)l * (1.0f / 4096.0f));
    cf Om = cmk(cosf(ang), sinf(ang));
    cf den = cmk(1.0f + Om.x, Om.y);
    cf num = cmk(1.0f - Om.x, -Om.y);
    cf rden = crcp(den);
    sC[tid] = cml(cmk(2.0f, 0.0f), rden);
    cf g = cml(num, rden);
    float sc = 2.0f / stepv;
    sG[tid] = cmk(g.x * sc, g.y * sc);
  }
  __syncthreads();
  for (int it = tid; it < 512; it += 256){
    int n = it >> 3, ll = it & 7;
    sInv[n][ll] = crcp(csb(sG[ll], sLam[n]));
  }
  __syncthreads();
  if (tid < 8){
    cf k10 = cmk(0,0), k11 = cmk(0,0);
    for (int n = 0; n < 64; n++){
      k10 = cad(k10, cml(sQB[n], sInv[n][tid]));
      k11 = cad(k11, cml(sQP[n], sInv[n][tid]));
    }
    sWood[tid] = cdv(k10, cmk(1.0f + k11.x, k11.y));
  }
  __syncthreads();
  int h = tid;
  cf a0[8], a1[8];
  #pragma unroll
  for (int ll = 0; ll < 8; ll++){ a0[ll] = cmk(0,0); a1[ll] = cmk(0,0); }
  for (int n = 0; n < 64; n++){
    cf cb = CBt[n * 256 + h];     // coalesced, L2-hot
    cf cp = CPt[n * 256 + h];
    #pragma unroll
    for (int ll = 0; ll < 8; ll++){
      cf iv = sInv[n][ll];
      a0[ll] = cad(a0[ll], cml(cb, iv));
      a1[ll] = cad(a1[ll], cml(cp, iv));
    }
  }
  cf* dst = A + (size_t)h * 4096 + l0;
  #pragma unroll
  for (int ll = 0; ll < 8; ll++){
    dst[ll] = cml(sC[ll], csb(a0[ll], cml(a1[ll], sWood[ll])));
  }
}

// ---------------- Kf pair tables (Sab): ifft4096 -> pack -> fft8192, 1024 threads ----------------
__global__ __launch_bounds__(1024) void k_kf(const cf* __restrict__ A, float4* __restrict__ Sab){
  extern __shared__ cf c[];   // 8192 cf
  int hp = blockIdx.x, tid = threadIdx.x;
  const cf* a1p = A + (size_t)(2 * hp) * 4096;
  const cf* a2p = a1p + 4096;
  for (int l = tid; l < 4096; l += 1024){
    int r = brev12(l);
    cf u = a1p[l], w = a2p[l];
    c[r] = cmk(u.x - w.y, u.y + w.x);          // A1 + i*A2, bitrev order
  }
  fft_dit_r4<4096, 1024>(c, 1.0f);             // unscaled ifft -> k1 + i*k2, natural
  float k1[4], k2[4];
  #pragma unroll
  for (int q = 0; q < 4; q++){
    cf w = c[tid + q * 1024];
    k1[q] = w.x * (1.0f / 4096.0f);
    k2[q] = w.y * (1.0f / 4096.0f);
  }
  __syncthreads();
  #pragma unroll
  for (int q = 0; q < 4; q++) c[tid + q * 1024] = cmk(k1[q], k2[q]);  // upper half via pad stage
  dif8192_pad_stage<1024>(c, -1.0f);
  fft_dif_r4<8192, 512, 1024>(c, -1.0f);       // Z = K1f + i*K2f, brev13 order
  float4* rec = Sab + (size_t)hp * 4097;
  const float sc = 0.5f * 0.5f * (1.0f / 8192.0f);
  #pragma unroll
  for (int q8 = 0; q8 < 4; q8++){
    int t = tid + 1024 * q8;
    int p = t << 1;
    int k = brev13(p);
    int qq = brev13((8192 - k) & 8191);
    cf Zp = c[p], Zq = c[qq];
    float K1x = (Zp.x + Zq.x), K1y = (Zp.y - Zq.y);
    float dx  = (Zp.x - Zq.x), dy  = (Zp.y + Zq.y);
    float K2x = dy, K2y = -dx;
    rec[t] = make_float4((K1x + K2x) * sc, (K1y + K2y) * sc,
                         (K1x - K2x) * sc, (K1y - K2y) * sc);
  }
  if (tid == 0){
    cf Z1 = c[1];
    float K1x = 2.0f * Z1.x, K2x = 2.0f * Z1.y;
    rec[4096] = make_float4((K1x + K2x) * sc, 0.0f, (K1x - K2x) * sc, 0.0f);
  }
}

// ---------------- conv: single 8192 FFT, 512 threads x 16 cf, one shuffle bit ----------------
// M0: n = t + 512r ; M1: n = (t>>5)*512 + u*32 + (t&31) ; M2: n = u2 + t*16 (16-cf runs)
// bit 4 via shfl_xor(1). LDS slot = pidx(n) = n + 6*(n>>5). slot p <-> bin brev13(p).
__global__ __launch_bounds__(512) void k_conv(const float* __restrict__ xT,
                                              const float4* __restrict__ Sab,
                                              const float* __restrict__ Dp,
                                              ushort* __restrict__ y1h,
                                              ushort* __restrict__ y1l){
  __shared__ __align__(16) cf c[9728];
  int blk = blockIdx.x;
  int b = blk >> 7, hp = blk & 127;
  int t = threadIdx.x;                 // 0..511
  int cl = t & 31;
  int m1b = (t >> 5) * 512 + cl;       // M1 base (u*32 added per element)
  int cb  = pidx(t << 4);              // M2 run base (16 cf contiguous, 16B aligned)
  const float* xs1 = xT + ((size_t)(b * 256 + 2 * hp)) * 4096;
  const float* xs2 = xs1 + 4096;
  cf v[16];
  #pragma unroll
  for (int r = 0; r < 8; r++){
    int n = t + 512 * r;
    v[r] = cmk(xs1[n], xs2[n]);
  }
  // ================= FORWARD (sign = -1) =================
  // bit 12 (zero-pad collapse)
  #pragma unroll
  for (int r = 0; r < 8; r++)
    v[r + 8] = cml(v[r], twid((float)(t + 512 * r) * (1.0f / 4096.0f), -1.0f));
  // bits 11,10 (S=1024 -> r-stride 2), both halves share twiddle
  #pragma unroll
  for (int r0 = 0; r0 < 2; r0++){
    cf w1 = twid((float)(t + 512 * r0) * (1.0f / 2048.0f), -1.0f);
    dif4q(v[r0], v[r0 + 2], v[r0 + 4], v[r0 + 6], w1, -1.0f);
    dif4q(v[8 + r0], v[8 + r0 + 2], v[8 + r0 + 4], v[8 + r0 + 6], w1, -1.0f);
  }
  // bit 9 (S=512 -> r-stride 1)
  {
    cf tw = twid((float)t * (1.0f / 512.0f), -1.0f);
    #pragma unroll
    for (int g = 0; g < 16; g += 2){
      cf lo = cad(v[g], v[g + 1]);
      cf hi = cml(csb(v[g], v[g + 1]), tw);
      v[g] = lo; v[g + 1] = hi;
    }
  }
  // T1: write M0, read M1
  #pragma unroll
  for (int r = 0; r < 16; r++) c[pidx(t + 512 * r)] = v[r];
  __syncthreads();
  #pragma unroll
  for (int u = 0; u < 16; u++) v[u] = c[pidx(m1b + u * 32)];
  // bits 8,7 (S=128 -> u-stride 4)
  #pragma unroll
  for (int u0 = 0; u0 < 4; u0++){
    cf w1 = twid((float)(cl + 32 * u0) * (1.0f / 256.0f), -1.0f);
    dif4q(v[u0], v[u0 + 4], v[u0 + 8], v[u0 + 12], w1, -1.0f);
  }
  // bits 6,5 (S=32 -> u-stride 1)
  {
    cf w1 = twid((float)cl * (1.0f / 64.0f), -1.0f);
    #pragma unroll
    for (int g = 0; g < 16; g += 4)
      dif4q(v[g], v[g + 1], v[g + 2], v[g + 3], w1, -1.0f);
  }
  // write M1 (own slots), barrier, read M2 (contiguous)
  #pragma unroll
  for (int u = 0; u < 16; u++) c[pidx(m1b + u * 32)] = v[u];
  __syncthreads();
  #pragma unroll
  for (int k = 0; k < 8; k++){
    float4 q0 = *(const float4*)&c[cb + 2 * k];
    v[2 * k]     = cmk(q0.x, q0.y);
    v[2 * k + 1] = cmk(q0.z, q0.w);
  }
  // bit 4 (S=16 -> lane bit 0 of t)
  {
    bool hb = (t & 1) != 0;
    #pragma unroll
    for (int u2 = 0; u2 < 16; u2++){
      cf o = shflx(v[u2], 1);
      cf tw = twid((float)u2 * (1.0f / 16.0f), -1.0f);
      v[u2] = hb ? cml(csb(o, v[u2]), tw) : cad(v[u2], o);
    }
  }
  // bits 3,2 (S=4 -> u2-stride 4)
  #pragma unroll
  for (int u0 = 0; u0 < 4; u0++){
    cf w1 = twid((float)u0 * 0.125f, -1.0f);
    dif4q(v[u0], v[u0 + 4], v[u0 + 8], v[u0 + 12], w1, -1.0f);
  }
  // bits 1,0 (unit twiddle)
  #pragma unroll
  for (int g = 0; g < 16; g += 4) dif4q0(v[g], v[g + 1], v[g + 2], v[g + 3], -1.0f);
  // write M2
  #pragma unroll
  for (int k = 0; k < 8; k++)
    *(float4*)&c[cb + 2 * k] = make_float4(v[2*k].x, v[2*k].y, v[2*k+1].x, v[2*k+1].y);
  __syncthreads();
  // ================= pointwise (brev13 pairing) =================
  {
    const float4* rec = Sab + (size_t)hp * 4097;
    #pragma unroll
    for (int q8 = 0; q8 < 8; q8++){
      int th = t + 512 * q8;
      int p = th << 1;
      int k = brev13(p);
      int qq = brev13((8192 - k) & 8191);
      int pi = pidx(p), qi = pidx(qq);
      cf Zp = c[pi], Zq = c[qi];
      float4 r0 = rec[th];
      cf Sap = cmk(r0.x, r0.y), Sbp = cmk(r0.z, r0.w);
      c[pi] = cad(cml(Zp, Sap), cml(cjg(Zq), Sbp));
      c[qi] = cad(cml(Zq, cjg(Sap)), cml(cjg(Zp), cjg(Sbp)));
    }
    if (t == 0){
      float4 e = rec[4096];
      cf Z1 = c[pidx(1)];
      c[pidx(1)] = cad(cml(Z1, cmk(e.x, e.y)), cml(cjg(Z1), cmk(e.z, e.w)));
    }
  }
  __syncthreads();
  // ================= INVERSE (sign = +1) =================
  #pragma unroll
  for (int k = 0; k < 8; k++){
    float4 q0 = *(const float4*)&c[cb + 2 * k];
    v[2 * k]     = cmk(q0.x, q0.y);
    v[2 * k + 1] = cmk(q0.z, q0.w);
  }
  // bits 1,0
  #pragma unroll
  for (int g = 0; g < 16; g += 4) dit4q0(v[g], v[g + 1], v[g + 2], v[g + 3], 1.0f);
  // bits 3,2
  #pragma unroll
  for (int u0 = 0; u0 < 4; u0++){
    cf w1 = twid((float)u0 * 0.125f, 1.0f);
    dit4q(v[u0], v[u0 + 4], v[u0 + 8], v[u0 + 12], w1, 1.0f);
  }
  // bit 4 (DIT shuffle)
  {
    bool hb = (t & 1) != 0;
    #pragma unroll
    for (int u2 = 0; u2 < 16; u2++){
      cf o = shflx(v[u2], 1);
      cf w = twid((float)u2 * (1.0f / 16.0f), 1.0f);
      cf whv = cml(w, hb ? v[u2] : o);
      v[u2] = hb ? csb(o, whv) : cad(v[u2], whv);
    }
  }
  // write M2, barrier, read M1
  #pragma unroll
  for (int k = 0; k < 8; k++)
    *(float4*)&c[cb + 2 * k] = make_float4(v[2*k].x, v[2*k].y, v[2*k+1].x, v[2*k+1].y);
  __syncthreads();
  #pragma unroll
  for (int u = 0; u < 16; u++) v[u] = c[pidx(m1b + u * 32)];
  // bits 6,5
  {
    cf w1 = twid((float)cl * (1.0f / 64.0f), 1.0f);
    #pragma unroll
    for (int g = 0; g < 16; g += 4)
      dit4q(v[g], v[g + 1], v[g + 2], v[g + 3], w1, 1.0f);
  }
  // bits 8,7
  #pragma unroll
  for (int u0 = 0; u0 < 4; u0++){
    cf w1 = twid((float)(cl + 32 * u0) * (1.0f / 256.0f), 1.0f);
    dit4q(v[u0], v[u0 + 4], v[u0 + 8], v[u0 + 12], w1, 1.0f);
  }
  // write M1, barrier, read M0
  #pragma unroll
  for (int u = 0; u < 16; u++) c[pidx(m1b + u * 32)] = v[u];
  __syncthreads();
  #pragma unroll
  for (int r = 0; r < 16; r++) v[r] = c[pidx(t + 512 * r)];
  // bit 9
  {
    cf tw = twid((float)t * (1.0f / 512.0f), 1.0f);
    #pragma unroll
    for (int g = 0; g < 16; g += 2){
      cf tb = cml(v[g + 1], tw);
      cf a0 = v[g];
      v[g] = cad(a0, tb);
      v[g + 1] = csb(a0, tb);
    }
  }
  // bits 11,10
  #pragma unroll
  for (int r0 = 0; r0 < 2; r0++){
    cf w1 = twid((float)(t + 512 * r0) * (1.0f / 2048.0f), 1.0f);
    dit4q(v[r0], v[r0 + 2], v[r0 + 4], v[r0 + 6], w1, 1.0f);
    dit4q(v[8 + r0], v[8 + r0 + 2], v[8 + r0 + 4], v[8 + r0 + 6], w1, 1.0f);
  }
  // bit 12 combine + epilogue
  float Dv = Dp[0];
  size_t base = ((size_t)(b * 256 + 2 * hp)) * 4096;
  #pragma unroll
  for (int r = 0; r < 8; r++){
    int n = t + 512 * r;
    cf w = cad(v[r], cml(v[r + 8], twid((float)n * (1.0f / 4096.0f), 1.0f)));
    float z1 = geluf(fmaf(Dv, xs1[n], w.x));
    float z2 = geluf(fmaf(Dv, xs2[n], w.y));
    ushort h0, l0, h1u, l1;
    bfsplit(z1, &h0, &l0);
    bfsplit(z2, &h1u, &l1);
    y1h[base + n] = h0;         y1l[base + n] = l0;
    y1h[base + 4096 + n] = h1u; y1l[base + 4096 + n] = l1;
  }
}

// ---------------- MFMA split-bf16 GEMM + gelu + skip + LayerNorm + max|y| ----------------
__global__ __launch_bounds__(256, 3) void k_gemm_ln(
    const ushort* __restrict__ y1h, const ushort* __restrict__ y1l,
    const ushort* __restrict__ Wh, const ushort* __restrict__ Wl,
    const float* __restrict__ bfc, const float* __restrict__ x,
    const float* __restrict__ lng, const float* __restrict__ lnb,
    float* __restrict__ yout, unsigned* __restrict__ ymax)
{
  __shared__ ushort sY[2][64 * 40];
  __shared__ float red1[64][4], red2[64][4];
  int tid = threadIdx.x;
  int l = tid & 63;
  int w = tid >> 6;
  int blk = blockIdx.x;
  int b = blk >> 6;
  int t0 = (blk & 63) * 64;
  int g = l >> 4, cc = l & 15;

  f32x4 acc[4][4];
  #pragma unroll
  for (int m = 0; m < 4; m++)
    #pragma unroll
    for (int n = 0; n < 4; n++)
      acc[m][n] = (f32x4){0.0f, 0.0f, 0.0f, 0.0f};

  int kk = tid >> 3, ts = (tid & 7) * 8;

  #pragma unroll 1
  for (int kc = 0; kc < 256; kc += 32){
    __syncthreads();
    {
      size_t gb = ((size_t)(b * 256 + kc + kk)) * 4096 + t0 + ts;
      float4 vh = *(const float4*)(y1h + gb);
      float4 vl = *(const float4*)(y1l + gb);
      const ushort* ph = (const ushort*)&vh;
      const ushort* pl = (const ushort*)&vl;
      int kblk = kk >> 3, kin = kk & 7;
      #pragma unroll
      for (int e = 0; e < 8; e++){
        int t = ts + e;
        int idx = t * 40 + ((kblk ^ ((t >> 3) & 3)) << 3) + kin;
        sY[0][idx] = ph[e];
        sY[1][idx] = pl[e];
      }
    }
    __syncthreads();
    bf16x8 afh[4], afl[4];
    #pragma unroll
    for (int m = 0; m < 4; m++){
      int t = m * 16 + cc;
      int idx = t * 40 + ((g ^ ((t >> 3) & 3)) << 3);
      afh[m] = *(bf16x8*)&sY[0][idx];
      afl[m] = *(bf16x8*)&sY[1][idx];
    }
    #pragma unroll
    for (int n = 0; n < 4; n++){
      size_t wj = (size_t)(w * 64 + n * 16 + cc) * 256 + kc + g * 8;
      bf16x8 bh = *(const bf16x8*)(Wh + wj);
      bf16x8 bl = *(const bf16x8*)(Wl + wj);
      #pragma unroll
      for (int m = 0; m < 4; m++){
        acc[m][n] = __builtin_amdgcn_mfma_f32_16x16x32_bf16(afh[m], bh, acc[m][n], 0, 0, 0);
        acc[m][n] = __builtin_amdgcn_mfma_f32_16x16x32_bf16(afh[m], bl, acc[m][n], 0, 0, 0);
        acc[m][n] = __builtin_amdgcn_mfma_f32_16x16x32_bf16(afl[m], bh, acc[m][n], 0, 0, 0);
      }
    }
  }

  float bj[4], gj[4], lj[4];
  #pragma unroll
  for (int n = 0; n < 4; n++){
    int j = w * 64 + n * 16 + cc;
    bj[n] = bfc[j]; gj[n] = lng[j]; lj[n] = lnb[j];
  }
  #pragma unroll
  for (int m = 0; m < 4; m++){
    #pragma unroll
    for (int r = 0; r < 4; r++){
      int tl = m * 16 + g * 4 + r;
      size_t rowb = ((size_t)(b * 4096 + t0 + tl)) * 256;
      float ss = 0.0f, sq = 0.0f;
      #pragma unroll
      for (int n = 0; n < 4; n++){
        float z = geluf(acc[m][n][r] + bj[n]) + x[rowb + w * 64 + n * 16 + cc];
        acc[m][n][r] = z;
        ss += z; sq = fmaf(z, z, sq);
      }
      #pragma unroll
      for (int msk = 1; msk < 16; msk <<= 1){
        ss += __shfl_xor(ss, msk);
        sq += __shfl_xor(sq, msk);
      }
      if (cc == 0){ red1[tl][w] = ss; red2[tl][w] = sq; }
    }
  }
  __syncthreads();
  float jm[4] = {0.0f, 0.0f, 0.0f, 0.0f};
  #pragma unroll
  for (int m = 0; m < 4; m++){
    #pragma unroll
    for (int r = 0; r < 4; r++){
      int tl = m * 16 + g * 4 + r;
      float ts1 = red1[tl][0] + red1[tl][1] + red1[tl][2] + red1[tl][3];
      float ts2 = red2[tl][0] + red2[tl][1] + red2[tl][2] + red2[tl][3];
      float mu = ts1 * (1.0f / 256.0f);
      float var = ts2 * (1.0f / 256.0f) - mu * mu;
      float rstd = rsqrtf(var + 1e-5f);
      size_t rowb = ((size_t)(b * 4096 + t0 + tl)) * 256;
      #pragma unroll
      for (int n = 0; n < 4; n++){
        float yv = (acc[m][n][r] - mu) * rstd * gj[n] + lj[n];
        yout[rowb + w * 64 + n * 16 + cc] = yv;
        jm[n] = fmaxf(jm[n], fabsf(yv));
      }
    }
  }
  #pragma unroll
  for (int n = 0; n < 4; n++){
    jm[n] = fmaxf(jm[n], __shfl_xor(jm[n], 16));
    jm[n] = fmaxf(jm[n], __shfl_xor(jm[n], 32));
  }
  if (g == 0){
    #pragma unroll
    for (int n = 0; n < 4; n++)
      atomicMax(&ymax[b * 256 + w * 64 + n * 16 + cc], __float_as_uint(jm[n]));
  }
}

// ---------------- final ratio ----------------
__global__ void k_ratio(const unsigned* __restrict__ ymax, const unsigned* __restrict__ xmax,
                        float* __restrict__ out){
  int i = blockIdx.x * 256 + threadIdx.x;
  if (i < 2048){
    float ym = __uint_as_float(ymax[i]);
    float xm = __uint_as_float(xmax[i]);
    out[8388608 + i] = ym / (xm + 1e-6f);
  }
}

extern "C" void kernel_launch(void* const* d_in, const int* in_sizes, int n_in,
                              void* d_out, int out_size, void* d_ws, size_t ws_size,
                              hipStream_t stream)
{
  const float* x    = (const float*)d_in[0];
  const float* Lr   = (const float*)d_in[1];
  const float* Li   = (const float*)d_in[2];
  const float* Pr   = (const float*)d_in[3];
  const float* Pi   = (const float*)d_in[4];
  const float* Qr   = (const float*)d_in[5];
  const float* Qi   = (const float*)d_in[6];
  const float* Br   = (const float*)d_in[7];
  const float* Bi   = (const float*)d_in[8];
  const float* Cr   = (const float*)d_in[9];
  const float* Ci   = (const float*)d_in[10];
  const float* stp  = (const float*)d_in[11];
  const float* Dp   = (const float*)d_in[12];
  const float* Wfc  = (const float*)d_in[13];
  const float* bfc  = (const float*)d_in[14];
  const float* lng  = (const float*)d_in[15];
  const float* lnb  = (const float*)d_in[16];

  char* ws = (char*)d_ws;
  float*    xT   = (float*)(ws);                                     // 32 MB
  float4*   Sab  = (float4*)(ws + ((size_t)32 << 20));               // ~8.4 MB (128*4097*16)
  cf*       A    = (cf*)(ws + ((size_t)41 << 20));                   // 8 MB (dead after k_kf)
  ushort*   y1h  = (ushort*)(ws + ((size_t)41 << 20));               // 16 MB (overlays A)
  ushort*   y1l  = (ushort*)(ws + ((size_t)57 << 20));               // 16 MB
  ushort*   Wh   = (ushort*)(ws + ((size_t)73 << 20));               // 128 KB
  ushort*   Wl   = (ushort*)(ws + ((size_t)73 << 20) + (128u << 10));
  unsigned* xmax = (unsigned*)(ws + ((size_t)73 << 20) + (256u << 10));
  unsigned* ymax = xmax + 2048;
  cf*       CBt  = (cf*)(ws + ((size_t)74 << 20));                   // 128 KB (64 n x 256 h)
  cf*       CPt  = (cf*)(ws + ((size_t)74 << 20) + (128u << 10));    // 128 KB

  k_wsplit<<<256, 256, 0, stream>>>(Wfc, Wh, Wl, xmax, ymax, Cr, Ci, Br, Bi, Pr, Pi, CBt, CPt);
  dim3 gt(64, 4, 8);
  k_transpose_x<<<gt, 256, 0, stream>>>(x, xT, xmax);
  k_cauchy<<<512, 256, 0, stream>>>(Lr, Li, Pr, Pi, Qr, Qi, Br, Bi, CBt, CPt, stp, A);
  k_kf<<<128, 1024, 65536, stream>>>(A, Sab);
  k_conv<<<1024, 512, 0, stream>>>(xT, Sab, Dp, y1h, y1l);
  k_gemm_ln<<<512, 256, 0, stream>>>(y1h, y1l, Wh, Wl, bfc, x, lng, lnb, (float*)d_out, ymax);
  k_ratio<<<8, 256, 0, stream>>>(ymax, xmax, (float*)d_out);
}

// Round 18
// 173.194 us; speedup vs baseline: 1.0117x; 1.0117x over previous
//
#include <hip/hip_runtime.h>
#include <math.h>

typedef float2 cf;
typedef float vf2 __attribute__((ext_vector_type(2)));
typedef __attribute__((ext_vector_type(8))) short bf16x8;
typedef __attribute__((ext_vector_type(4))) float f32x4;

__device__ __forceinline__ cf cmk(float x, float y){ cf r; r.x=x; r.y=y; return r; }

// ---- packed-FP32 complex primitives (VOP3P dual-issue; gfx90a+/gfx950) ----
__device__ __forceinline__ cf cad(cf a, cf b){
  vf2 av, bv, rv;
  av.x = a.x; av.y = a.y; bv.x = b.x; bv.y = b.y;
  asm("v_pk_add_f32 %0, %1, %2" : "=v"(rv) : "v"(av), "v"(bv));
  return cmk(rv.x, rv.y);
}
__device__ __forceinline__ cf csb(cf a, cf b){
  vf2 av, bv, rv;
  av.x = a.x; av.y = a.y; bv.x = b.x; bv.y = b.y;
  asm("v_pk_add_f32 %0, %1, %2 neg_lo:[0,1] neg_hi:[0,1]" : "=v"(rv) : "v"(av), "v"(bv));
  return cmk(rv.x, rv.y);
}
// (a.x*b.x - a.y*b.y, a.x*b.y + a.y*b.x) in 2 packed insts
__device__ __forceinline__ cf cml(cf a, cf b){
  vf2 av, bv, rv;
  av.x = a.x; av.y = a.y; bv.x = b.x; bv.y = b.y;
  asm("v_pk_mul_f32 %0, %1, %2 op_sel:[0,0] op_sel_hi:[0,1]\n\t"
      "v_pk_fma_f32 %0, %1, %2, %0 op_sel:[1,1,0] op_sel_hi:[1,0,1] neg_lo:[1,0,0]"
      : "=&v"(rv) : "v"(av), "v"(bv));
  return cmk(rv.x, rv.y);
}

__device__ __forceinline__ cf cjg(cf a){ return cmk(a.x, -a.y); }
__device__ __forceinline__ cf crcp(cf d){ float r = 1.0f/(d.x*d.x + d.y*d.y); return cmk(d.x*r, -d.y*r); }
__device__ __forceinline__ cf cdv(cf n, cf d){ return cml(n, crcp(d)); }
__device__ __forceinline__ float geluf(float z){ return 0.5f*z*(1.0f + erff(z*0.70710678118654752f)); }

// exp(sign*i*pi*f) via native v_sin/v_cos (input in revolutions)
__device__ __forceinline__ cf twid(float f, float sign){
  float h = f * 0.5f;
  float s = __builtin_amdgcn_sinf(h);
  float c0 = __builtin_amdgcn_cosf(h);
  return cmk(c0, sign * s);
}

__device__ __forceinline__ void bfsplit(float v, ushort* h, ushort* l){
  unsigned u = __float_as_uint(v);
  unsigned hr = (u + 0x7FFFu + ((u >> 16) & 1u)) & 0xFFFF0000u;
  *h = (ushort)(hr >> 16);
  float lv = v - __uint_as_float(hr);
  unsigned u2 = __float_as_uint(lv);
  *l = (ushort)((u2 + 0x7FFFu + ((u2 >> 16) & 1u)) >> 16);
}

// radix-4 butterflies on a register quad (element strides 0,S,2S,3S), w1 = twid(j/(2S))
__device__ __forceinline__ void dif4q(cf& q0, cf& q1, cf& q2, cf& q3, cf w1, float sign){
  cf w2 = cml(w1, w1);
  cf a1 = cad(q0, q2);
  cf c1 = cml(csb(q0, q2), w1);
  cf b1 = cad(q1, q3);
  cf d1 = cml(csb(q1, q3), cmk(-sign*w1.y, sign*w1.x));
  q0 = cad(a1, b1);
  q1 = cml(csb(a1, b1), w2);
  q2 = cad(c1, d1);
  q3 = cml(csb(c1, d1), w2);
}
__device__ __forceinline__ void dit4q(cf& q0, cf& q1, cf& q2, cf& q3, cf w1, float sign){
  cf w2 = cml(w1, w1);
  cf t1 = cml(q1, w2);
  cf a1 = cad(q0, t1), b1 = csb(q0, t1);
  cf t2 = cml(q3, w2);
  cf c1 = cad(q2, t2), d1 = csb(q2, t2);
  cf v1 = cml(c1, w1);
  cf v2 = cml(d1, cmk(-sign*w1.y, sign*w1.x));
  q0 = cad(a1, v1);
  q2 = csb(a1, v1);
  q1 = cad(b1, v2);
  q3 = csb(b1, v2);
}
// unit-twiddle specializations (w1 = 1)
__device__ __forceinline__ void dif4q0(cf& q0, cf& q1, cf& q2, cf& q3, float sign){
  cf a1 = cad(q0, q2), c1 = csb(q0, q2);
  cf b1 = cad(q1, q3), d0 = csb(q1, q3);
  cf d1 = cmk(-sign*d0.y, sign*d0.x);
  q0 = cad(a1, b1); q1 = csb(a1, b1);
  q2 = cad(c1, d1); q3 = csb(c1, d1);
}
__device__ __forceinline__ void dit4q0(cf& q0, cf& q1, cf& q2, cf& q3, float sign){
  cf a1 = cad(q0, q1), b1 = csb(q0, q1);
  cf c1 = cad(q2, q3), d0 = csb(q2, q3);
  cf v2 = cmk(-sign*d0.y, sign*d0.x);
  q0 = cad(a1, c1); q2 = csb(a1, c1);
  q1 = cad(b1, v2); q3 = csb(b1, v2);
}

__device__ __forceinline__ int brev12(int x){ return (int)(__brev((unsigned)x) >> 20); }
__device__ __forceinline__ int brev13(int x){ return (int)(__brev((unsigned)x) >> 19); }
// bank-spreading pad: +2 cf per 32-cf block
__device__ __forceinline__ int pidx(int n){ return n + 2*(n>>5); }

// ---------------- legacy LDS FFT templates (k_kf only), TP-parameterized ----------------
template<int N, int SSTART, int TP>
__device__ void fft_dif_r4(cf* __restrict__ a, float sign){
  #pragma unroll
  for (int s = SSTART; s >= 1; s >>= 2){
    __syncthreads();
    #pragma unroll
    for (int g = 0; g < (N >> 2) / TP; g++){
      int w = (int)threadIdx.x + g * TP;
      int j = w & (s - 1);
      int base = ((w & ~(s - 1)) << 2) | j;
      cf A0 = a[base], B0 = a[base + s], C0 = a[base + 2*s], D0 = a[base + 3*s];
      cf w1 = twid((float)j / (float)(2 * s), sign);
      cf w2 = cml(w1, w1);
      cf a1 = cad(A0, C0);
      cf c1 = cml(csb(A0, C0), w1);
      cf b1 = cad(B0, D0);
      cf d1 = cml(csb(B0, D0), cmk(-sign * w1.y, sign * w1.x));
      a[base]         = cad(a1, b1);
      a[base + s]     = cml(csb(a1, b1), w2);
      a[base + 2*s]   = cad(c1, d1);
      a[base + 3*s]   = cml(csb(c1, d1), w2);
    }
  }
  if constexpr ((__builtin_ctz(N) & 1) == 1){
    __syncthreads();
    #pragma unroll
    for (int g = 0; g < (N >> 1) / TP; g++){
      int w = (int)threadIdx.x + g * TP;
      int i = w << 1;
      cf u = a[i], v = a[i + 1];
      a[i] = cad(u, v);
      a[i + 1] = csb(u, v);
    }
  }
  __syncthreads();
}

template<int N, int TP>
__device__ void fft_dit_r4(cf* __restrict__ a, float sign){
  if constexpr ((__builtin_ctz(N) & 1) == 1){
    __syncthreads();
    #pragma unroll
    for (int g = 0; g < (N >> 1) / TP; g++){
      int w = (int)threadIdx.x + g * TP;
      int i = w << 1;
      cf u = a[i], v = a[i + 1];
      a[i] = cad(u, v);
      a[i + 1] = csb(u, v);
    }
  }
  constexpr int S0 = ((__builtin_ctz(N) & 1) == 1) ? 2 : 1;
  #pragma unroll
  for (int s = S0; s <= (N >> 2); s <<= 2){
    __syncthreads();
    #pragma unroll
    for (int g = 0; g < (N >> 2) / TP; g++){
      int w = (int)threadIdx.x + g * TP;
      int j = w & (s - 1);
      int base = ((w & ~(s - 1)) << 2) | j;
      cf A0 = a[base], B0 = a[base + s], C0 = a[base + 2*s], D0 = a[base + 3*s];
      cf w1 = twid((float)j / (float)(2 * s), sign);
      cf w2 = cml(w1, w1);
      cf t1 = cml(B0, w2);
      cf a1 = cad(A0, t1), b1 = csb(A0, t1);
      cf t2 = cml(D0, w2);
      cf c1 = cad(C0, t2), d1 = csb(C0, t2);
      cf v1 = cml(c1, w1);
      cf v2 = cml(d1, cmk(-sign * w1.y, sign * w1.x));
      a[base]         = cad(a1, v1);
      a[base + 2*s]   = csb(a1, v1);
      a[base + s]     = cad(b1, v2);
      a[base + 3*s]   = csb(b1, v2);
    }
  }
  __syncthreads();
}

template<int TP>
__device__ void dif8192_pad_stage(cf* __restrict__ a, float sign){
  __syncthreads();
  #pragma unroll
  for (int g = 0; g < 2048 / TP; g++){
    int w = (int)threadIdx.x + g * TP;
    cf A0 = a[w], B0 = a[w + 2048];
    cf w1 = twid((float)w * (1.0f / 4096.0f), sign);
    cf w2 = cml(w1, w1);
    cf c1 = cml(A0, w1);
    cf d1 = cml(B0, cmk(-sign * w1.y, sign * w1.x));
    a[w]        = cad(A0, B0);
    a[w + 2048] = cml(csb(A0, B0), w2);
    a[w + 4096] = cad(c1, d1);
    a[w + 6144] = cml(csb(c1, d1), w2);
  }
}

// ---------------- transpose x (B,L,H)->(B,H,L), fused max|x| ----------------
__global__ __launch_bounds__(256) void k_transpose_x(const float* __restrict__ x,
                                                     float* __restrict__ xT,
                                                     unsigned* __restrict__ xmax){
  __shared__ float tile[64][65];
  __shared__ float red[64][4];
  int b = blockIdx.z;
  int t0 = blockIdx.x * 64;
  int h0 = blockIdx.y * 64;
  int hc = threadIdx.x & 63, tg = threadIdx.x >> 6;
  float pmax = 0.0f;
  #pragma unroll
  for (int q = 0; q < 16; q++){
    int tr = tg + q * 4;
    float v = x[((size_t)(b * 4096 + t0 + tr)) * 256 + h0 + hc];
    tile[tr][hc] = v;
    pmax = fmaxf(pmax, fabsf(v));
  }
  red[hc][tg] = pmax;
  __syncthreads();
  if (threadIdx.x < 64){
    float m = fmaxf(fmaxf(red[threadIdx.x][0], red[threadIdx.x][1]),
                    fmaxf(red[threadIdx.x][2], red[threadIdx.x][3]));
    atomicMax(&xmax[b * 256 + h0 + threadIdx.x], __float_as_uint(m));
  }
  #pragma unroll
  for (int q = 0; q < 16; q++){
    int hr = tg + q * 4;
    xT[((size_t)(b * 256 + h0 + hr)) * 4096 + t0 + hc] = tile[hc][hr];
  }
}

// ---------------- W -> bf16 hi/lo planes + init atomic-max + Cauchy prep tables ----------------
__global__ void k_wsplit(const float* __restrict__ W, ushort* __restrict__ Wh, ushort* __restrict__ Wl,
                         unsigned* __restrict__ xmax, unsigned* __restrict__ ymax,
                         const float* __restrict__ Cr, const float* __restrict__ Ci,
                         const float* __restrict__ Br, const float* __restrict__ Bi,
                         const float* __restrict__ Pr, const float* __restrict__ Pi,
                         cf* __restrict__ CBt, cf* __restrict__ CPt){
  int i = blockIdx.x * 256 + threadIdx.x;
  if (i < 2048){ xmax[i] = 0u; ymax[i] = 0u; }
  if (i < 16384){                       // prep: CBt[n][h] = C[h][n]*B[n], CPt = C*P
    int n = i >> 8, h = i & 255;
    cf cc = cmk(Cr[h * 64 + n], Ci[h * 64 + n]);
    CBt[i] = cml(cc, cmk(Br[n], Bi[n]));
    CPt[i] = cml(cc, cmk(Pr[n], Pi[n]));
  }
  ushort h, l;
  bfsplit(W[i], &h, &l);
  Wh[i] = h; Wl[i] = l;
}

// ---------------- Cauchy (8 l per block, 512 blocks, coalesced, no spill) ----------------
__global__ __launch_bounds__(256, 2) void k_cauchy(
    const float* __restrict__ Lr, const float* __restrict__ Li,
    const float* __restrict__ Pr, const float* __restrict__ Pi,
    const float* __restrict__ Qr, const float* __restrict__ Qi,
    const float* __restrict__ Br, const float* __restrict__ Bi,
    const cf* __restrict__ CBt, const cf* __restrict__ CPt,
    const float* __restrict__ stepp, cf* __restrict__ A)
{
  __shared__ cf sLam[64], sQB[64], sQP[64];
  __shared__ cf sInv[64][8];
  __shared__ cf sWood[8], sC[8], sG[8];
  int tid = threadIdx.x;
  int l0 = blockIdx.x * 8;
  float stepv = fmaxf(stepp[0], 1e-6f);
  if (tid < 64){
    cf lam = cmk(Lr[tid], Li[tid]);
    cf b = cmk(Br[tid], Bi[tid]);
    cf p = cmk(Pr[tid], Pi[tid]);
    cf q = cmk(Qr[tid], Qi[tid]);
    sLam[tid] = lam;
    sQB[tid] = cml(q, b);
    sQP[tid] = cml(q, p);
  }
  __syncthreads();
  if (tid < 8){
    int l = l0 + tid;
    float ang = -6.2831855f * ((float)l * (1.0f / 4096.0f));
    cf Om = cmk(cosf(ang), sinf(ang));
    cf den = cmk(1.0f + Om.x, Om.y);
    cf num = cmk(1.0f - Om.x, -Om.y);
    cf rden = crcp(den);
    sC[tid] = cml(cmk(2.0f, 0.0f), rden);
    cf g = cml(num, rden);
    float sc = 2.0f / stepv;
    sG[tid] = cmk(g.x * sc, g.y * sc);
  }
  __syncthreads();
  for (int it = tid; it < 512; it += 256){
    int n = it >> 3, ll = it & 7;
    sInv[n][ll] = crcp(csb(sG[ll], sLam[n]));
  }
  __syncthreads();
  if (tid < 8){
    cf k10 = cmk(0,0), k11 = cmk(0,0);
    for (int n = 0; n < 64; n++){
      k10 = cad(k10, cml(sQB[n], sInv[n][tid]));
      k11 = cad(k11, cml(sQP[n], sInv[n][tid]));
    }
    sWood[tid] = cdv(k10, cmk(1.0f + k11.x, k11.y));
  }
  __syncthreads();
  int h = tid;
  cf a0[8], a1[8];
  #pragma unroll
  for (int ll = 0; ll < 8; ll++){ a0[ll] = cmk(0,0); a1[ll] = cmk(0,0); }
  for (int n = 0; n < 64; n++){
    cf cb = CBt[n * 256 + h];     // coalesced, L2-hot
    cf cp = CPt[n * 256 + h];
    #pragma unroll
    for (int ll = 0; ll < 8; ll++){
      cf iv = sInv[n][ll];
      a0[ll] = cad(a0[ll], cml(cb, iv));
      a1[ll] = cad(a1[ll], cml(cp, iv));
    }
  }
  cf* dst = A + (size_t)h * 4096 + l0;
  #pragma unroll
  for (int ll = 0; ll < 8; ll++){
    dst[ll] = cml(sC[ll], csb(a0[ll], cml(a1[ll], sWood[ll])));
  }
}

// ---------------- Kf pair tables (Sab): ifft4096 -> pack -> fft8192, 1024 threads ----------------
__global__ __launch_bounds__(1024) void k_kf(const cf* __restrict__ A, float4* __restrict__ Sab){
  extern __shared__ cf c[];   // 8192 cf
  int hp = blockIdx.x, tid = threadIdx.x;
  const cf* a1p = A + (size_t)(2 * hp) * 4096;
  const cf* a2p = a1p + 4096;
  for (int l = tid; l < 4096; l += 1024){
    int r = brev12(l);
    cf u = a1p[l], w = a2p[l];
    c[r] = cmk(u.x - w.y, u.y + w.x);          // A1 + i*A2, bitrev order
  }
  fft_dit_r4<4096, 1024>(c, 1.0f);             // unscaled ifft -> k1 + i*k2, natural
  float k1[4], k2[4];
  #pragma unroll
  for (int q = 0; q < 4; q++){
    cf w = c[tid + q * 1024];
    k1[q] = w.x * (1.0f / 4096.0f);
    k2[q] = w.y * (1.0f / 4096.0f);
  }
  __syncthreads();
  #pragma unroll
  for (int q = 0; q < 4; q++) c[tid + q * 1024] = cmk(k1[q], k2[q]);  // upper half via pad stage
  dif8192_pad_stage<1024>(c, -1.0f);
  fft_dif_r4<8192, 512, 1024>(c, -1.0f);       // Z = K1f + i*K2f, brev13 order
  float4* rec = Sab + (size_t)hp * 4097;
  const float sc = 0.5f * 0.5f * (1.0f / 8192.0f);
  #pragma unroll
  for (int q8 = 0; q8 < 4; q8++){
    int t = tid + 1024 * q8;
    int p = t << 1;
    int k = brev13(p);
    int qq = brev13((8192 - k) & 8191);
    cf Zp = c[p], Zq = c[qq];
    float K1x = (Zp.x + Zq.x), K1y = (Zp.y - Zq.y);
    float dx  = (Zp.x - Zq.x), dy  = (Zp.y + Zq.y);
    float K2x = dy, K2y = -dx;
    rec[t] = make_float4((K1x + K2x) * sc, (K1y + K2y) * sc,
                         (K1x - K2x) * sc, (K1y - K2y) * sc);
  }
  if (tid == 0){
    cf Z1 = c[1];
    float K1x = 2.0f * Z1.x, K2x = 2.0f * Z1.y;
    rec[4096] = make_float4((K1x + K2x) * sc, 0.0f, (K1x - K2x) * sc, 0.0f);
  }
}

// ---------------- conv: single 8192 FFT, 256 threads x 32 cf, shuffle-free ----------------
__global__ __launch_bounds__(256) void k_conv(const float* __restrict__ xT,
                                              const float4* __restrict__ Sab,
                                              const float* __restrict__ Dp,
                                              ushort* __restrict__ y1h,
                                              ushort* __restrict__ y1l){
  __shared__ __align__(16) cf c[8704];
  int blk = blockIdx.x;
  int b = blk >> 7, hp = blk & 127;
  int t = threadIdx.x;
  int lo4 = t & 15, hiT = t >> 4;
  int base0 = lo4 + ((hiT << 1) << 8);
  int base1 = lo4 + ((((hiT << 1) | 1)) << 8);
  int cb0 = pidx((t << 1) << 4);
  int cb1 = pidx(((t << 1) | 1) << 4);
  const float* xs1 = xT + ((size_t)(b * 256 + 2 * hp)) * 4096;
  const float* xs2 = xs1 + 4096;
  cf v[32];
  #pragma unroll
  for (int r = 0; r < 16; r++){
    int n = t + 256 * r;
    v[r] = cmk(xs1[n], xs2[n]);
  }
  // ================= FORWARD (sign = -1) =================
  #pragma unroll
  for (int r = 0; r < 16; r++)
    v[r + 16] = cml(v[r], twid((float)(t + 256 * r) * (1.0f / 4096.0f), -1.0f));
  #pragma unroll
  for (int r0 = 0; r0 < 4; r0++){
    cf w1 = twid((float)(t + 256 * r0) * (1.0f / 2048.0f), -1.0f);
    dif4q(v[r0], v[r0 + 4], v[r0 + 8], v[r0 + 12], w1, -1.0f);
    dif4q(v[16 + r0], v[16 + r0 + 4], v[16 + r0 + 8], v[16 + r0 + 12], w1, -1.0f);
  }
  {
    cf w1 = twid((float)t * (1.0f / 512.0f), -1.0f);
    #pragma unroll
    for (int g = 0; g < 32; g += 4)
      dif4q(v[g], v[g + 1], v[g + 2], v[g + 3], w1, -1.0f);
  }
  #pragma unroll
  for (int r = 0; r < 32; r++) c[pidx(t + 256 * r)] = v[r];
  __syncthreads();
  #pragma unroll
  for (int u = 0; u < 16; u++){
    v[u]      = c[pidx(base0 + (u << 4))];
    v[16 + u] = c[pidx(base1 + (u << 4))];
  }
  #pragma unroll
  for (int u0 = 0; u0 < 4; u0++){
    cf w1 = twid((float)(lo4 + (u0 << 4)) * (1.0f / 128.0f), -1.0f);
    dif4q(v[u0], v[u0 + 4], v[u0 + 8], v[u0 + 12], w1, -1.0f);
    dif4q(v[16 + u0], v[16 + u0 + 4], v[16 + u0 + 8], v[16 + u0 + 12], w1, -1.0f);
  }
  {
    cf w1 = twid((float)lo4 * (1.0f / 32.0f), -1.0f);
    #pragma unroll
    for (int g = 0; g < 32; g += 4)
      dif4q(v[g], v[g + 1], v[g + 2], v[g + 3], w1, -1.0f);
  }
  #pragma unroll
  for (int u = 0; u < 16; u++){
    c[pidx(base0 + (u << 4))] = v[u];
    c[pidx(base1 + (u << 4))] = v[16 + u];
  }
  __syncthreads();
  #pragma unroll
  for (int k = 0; k < 8; k++){
    float4 q0 = *(const float4*)&c[cb0 + 2 * k];
    float4 q1 = *(const float4*)&c[cb1 + 2 * k];
    v[2 * k]      = cmk(q0.x, q0.y); v[2 * k + 1]      = cmk(q0.z, q0.w);
    v[16 + 2 * k] = cmk(q1.x, q1.y); v[16 + 2 * k + 1] = cmk(q1.z, q1.w);
  }
  #pragma unroll
  for (int u0 = 0; u0 < 4; u0++){
    cf w1 = twid((float)u0 * 0.125f, -1.0f);
    dif4q(v[u0], v[u0 + 4], v[u0 + 8], v[u0 + 12], w1, -1.0f);
    dif4q(v[16 + u0], v[16 + u0 + 4], v[16 + u0 + 8], v[16 + u0 + 12], w1, -1.0f);
  }
  #pragma unroll
  for (int g = 0; g < 32; g += 4) dif4q0(v[g], v[g + 1], v[g + 2], v[g + 3], -1.0f);
  #pragma unroll
  for (int k = 0; k < 8; k++){
    *(float4*)&c[cb0 + 2 * k] = make_float4(v[2*k].x, v[2*k].y, v[2*k+1].x, v[2*k+1].y);
    *(float4*)&c[cb1 + 2 * k] = make_float4(v[16+2*k].x, v[16+2*k].y, v[16+2*k+1].x, v[16+2*k+1].y);
  }
  __syncthreads();
  // ================= pointwise (brev13 pairing) =================
  {
    const float4* rec = Sab + (size_t)hp * 4097;
    #pragma unroll
    for (int q8 = 0; q8 < 16; q8++){
      int th = t + 256 * q8;
      int p = th << 1;
      int k = brev13(p);
      int qq = brev13((8192 - k) & 8191);
      int pi = pidx(p), qi = pidx(qq);
      cf Zp = c[pi], Zq = c[qi];
      float4 r0 = rec[th];
      cf Sap = cmk(r0.x, r0.y), Sbp = cmk(r0.z, r0.w);
      c[pi] = cad(cml(Zp, Sap), cml(cjg(Zq), Sbp));
      c[qi] = cad(cml(Zq, cjg(Sap)), cml(cjg(Zp), cjg(Sbp)));
    }
    if (t == 0){
      float4 e = rec[4096];
      cf Z1 = c[pidx(1)];
      c[pidx(1)] = cad(cml(Z1, cmk(e.x, e.y)), cml(cjg(Z1), cmk(e.z, e.w)));
    }
  }
  __syncthreads();
  // ================= INVERSE (sign = +1) =================
  #pragma unroll
  for (int k = 0; k < 8; k++){
    float4 q0 = *(const float4*)&c[cb0 + 2 * k];
    float4 q1 = *(const float4*)&c[cb1 + 2 * k];
    v[2 * k]      = cmk(q0.x, q0.y); v[2 * k + 1]      = cmk(q0.z, q0.w);
    v[16 + 2 * k] = cmk(q1.x, q1.y); v[16 + 2 * k + 1] = cmk(q1.z, q1.w);
  }
  #pragma unroll
  for (int g = 0; g < 32; g += 4) dit4q0(v[g], v[g + 1], v[g + 2], v[g + 3], 1.0f);
  #pragma unroll
  for (int u0 = 0; u0 < 4; u0++){
    cf w1 = twid((float)u0 * 0.125f, 1.0f);
    dit4q(v[u0], v[u0 + 4], v[u0 + 8], v[u0 + 12], w1, 1.0f);
    dit4q(v[16 + u0], v[16 + u0 + 4], v[16 + u0 + 8], v[16 + u0 + 12], w1, 1.0f);
  }
  #pragma unroll
  for (int k = 0; k < 8; k++){
    *(float4*)&c[cb0 + 2 * k] = make_float4(v[2*k].x, v[2*k].y, v[2*k+1].x, v[2*k+1].y);
    *(float4*)&c[cb1 + 2 * k] = make_float4(v[16+2*k].x, v[16+2*k].y, v[16+2*k+1].x, v[16+2*k+1].y);
  }
  __syncthreads();
  #pragma unroll
  for (int u = 0; u < 16; u++){
    v[u]      = c[pidx(base0 + (u << 4))];
    v[16 + u] = c[pidx(base1 + (u << 4))];
  }
  {
    cf w1 = twid((float)lo4 * (1.0f / 32.0f), 1.0f);
    #pragma unroll
    for (int g = 0; g < 32; g += 4)
      dit4q(v[g], v[g + 1], v[g + 2], v[g + 3], w1, 1.0f);
  }
  #pragma unroll
  for (int u0 = 0; u0 < 4; u0++){
    cf w1 = twid((float)(lo4 + (u0 << 4)) * (1.0f / 128.0f), 1.0f);
    dit4q(v[u0], v[u0 + 4], v[u0 + 8], v[u0 + 12], w1, 1.0f);
    dit4q(v[16 + u0], v[16 + u0 + 4], v[16 + u0 + 8], v[16 + u0 + 12], w1, 1.0f);
  }
  #pragma unroll
  for (int u = 0; u < 16; u++){
    c[pidx(base0 + (u << 4))] = v[u];
    c[pidx(base1 + (u << 4))] = v[16 + u];
  }
  __syncthreads();
  #pragma unroll
  for (int r = 0; r < 32; r++) v[r] = c[pidx(t + 256 * r)];
  {
    cf w1 = twid((float)t * (1.0f / 512.0f), 1.0f);
    #pragma unroll
    for (int g = 0; g < 32; g += 4)
      dit4q(v[g], v[g + 1], v[g + 2], v[g + 3], w1, 1.0f);
  }
  #pragma unroll
  for (int r0 = 0; r0 < 4; r0++){
    cf w1 = twid((float)(t + 256 * r0) * (1.0f / 2048.0f), 1.0f);
    dit4q(v[r0], v[r0 + 4], v[r0 + 8], v[r0 + 12], w1, 1.0f);
    dit4q(v[16 + r0], v[16 + r0 + 4], v[16 + r0 + 8], v[16 + r0 + 12], w1, 1.0f);
  }
  float Dv = Dp[0];
  size_t base = ((size_t)(b * 256 + 2 * hp)) * 4096;
  #pragma unroll
  for (int r = 0; r < 16; r++){
    int n = t + 256 * r;
    cf w = cad(v[r], cml(v[r + 16], twid((float)n * (1.0f / 4096.0f), 1.0f)));
    float z1 = geluf(fmaf(Dv, xs1[n], w.x));
    float z2 = geluf(fmaf(Dv, xs2[n], w.y));
    ushort h0, l0, h1u, l1;
    bfsplit(z1, &h0, &l0);
    bfsplit(z2, &h1u, &l1);
    y1h[base + n] = h0;         y1l[base + n] = l0;
    y1h[base + 4096 + n] = h1u; y1l[base + 4096 + n] = l1;
  }
}

// ---------------- MFMA split-bf16 GEMM + gelu + skip + LayerNorm + max|y| ----------------
__global__ __launch_bounds__(256, 3) void k_gemm_ln(
    const ushort* __restrict__ y1h, const ushort* __restrict__ y1l,
    const ushort* __restrict__ Wh, const ushort* __restrict__ Wl,
    const float* __restrict__ bfc, const float* __restrict__ x,
    const float* __restrict__ lng, const float* __restrict__ lnb,
    float* __restrict__ yout, unsigned* __restrict__ ymax)
{
  __shared__ ushort sY[2][64 * 40];
  __shared__ float red1[64][4], red2[64][4];
  int tid = threadIdx.x;
  int l = tid & 63;
  int w = tid >> 6;
  int blk = blockIdx.x;
  int b = blk >> 6;
  int t0 = (blk & 63) * 64;
  int g = l >> 4, cc = l & 15;

  f32x4 acc[4][4];
  #pragma unroll
  for (int m = 0; m < 4; m++)
    #pragma unroll
    for (int n = 0; n < 4; n++)
      acc[m][n] = (f32x4){0.0f, 0.0f, 0.0f, 0.0f};

  int kk = tid >> 3, ts = (tid & 7) * 8;

  #pragma unroll 1
  for (int kc = 0; kc < 256; kc += 32){
    __syncthreads();
    {
      size_t gb = ((size_t)(b * 256 + kc + kk)) * 4096 + t0 + ts;
      float4 vh = *(const float4*)(y1h + gb);
      float4 vl = *(const float4*)(y1l + gb);
      const ushort* ph = (const ushort*)&vh;
      const ushort* pl = (const ushort*)&vl;
      int kblk = kk >> 3, kin = kk & 7;
      #pragma unroll
      for (int e = 0; e < 8; e++){
        int t = ts + e;
        int idx = t * 40 + ((kblk ^ ((t >> 3) & 3)) << 3) + kin;
        sY[0][idx] = ph[e];
        sY[1][idx] = pl[e];
      }
    }
    __syncthreads();
    bf16x8 afh[4], afl[4];
    #pragma unroll
    for (int m = 0; m < 4; m++){
      int t = m * 16 + cc;
      int idx = t * 40 + ((g ^ ((t >> 3) & 3)) << 3);
      afh[m] = *(bf16x8*)&sY[0][idx];
      afl[m] = *(bf16x8*)&sY[1][idx];
    }
    #pragma unroll
    for (int n = 0; n < 4; n++){
      size_t wj = (size_t)(w * 64 + n * 16 + cc) * 256 + kc + g * 8;
      bf16x8 bh = *(const bf16x8*)(Wh + wj);
      bf16x8 bl = *(const bf16x8*)(Wl + wj);
      #pragma unroll
      for (int m = 0; m < 4; m++){
        acc[m][n] = __builtin_amdgcn_mfma_f32_16x16x32_bf16(afh[m], bh, acc[m][n], 0, 0, 0);
        acc[m][n] = __builtin_amdgcn_mfma_f32_16x16x32_bf16(afh[m], bl, acc[m][n], 0, 0, 0);
        acc[m][n] = __builtin_amdgcn_mfma_f32_16x16x32_bf16(afl[m], bh, acc[m][n], 0, 0, 0);
      }
    }
  }

  float bj[4], gj[4], lj[4];
  #pragma unroll
  for (int n = 0; n < 4; n++){
    int j = w * 64 + n * 16 + cc;
    bj[n] = bfc[j]; gj[n] = lng[j]; lj[n] = lnb[j];
  }
  #pragma unroll
  for (int m = 0; m < 4; m++){
    #pragma unroll
    for (int r = 0; r < 4; r++){
      int tl = m * 16 + g * 4 + r;
      size_t rowb = ((size_t)(b * 4096 + t0 + tl)) * 256;
      float ss = 0.0f, sq = 0.0f;
      #pragma unroll
      for (int n = 0; n < 4; n++){
        float z = geluf(acc[m][n][r] + bj[n]) + x[rowb + w * 64 + n * 16 + cc];
        acc[m][n][r] = z;
        ss += z; sq = fmaf(z, z, sq);
      }
      #pragma unroll
      for (int msk = 1; msk < 16; msk <<= 1){
        ss += __shfl_xor(ss, msk);
        sq += __shfl_xor(sq, msk);
      }
      if (cc == 0){ red1[tl][w] = ss; red2[tl][w] = sq; }
    }
  }
  __syncthreads();
  float jm[4] = {0.0f, 0.0f, 0.0f, 0.0f};
  #pragma unroll
  for (int m = 0; m < 4; m++){
    #pragma unroll
    for (int r = 0; r < 4; r++){
      int tl = m * 16 + g * 4 + r;
      float ts1 = red1[tl][0] + red1[tl][1] + red1[tl][2] + red1[tl][3];
      float ts2 = red2[tl][0] + red2[tl][1] + red2[tl][2] + red2[tl][3];
      float mu = ts1 * (1.0f / 256.0f);
      float var = ts2 * (1.0f / 256.0f) - mu * mu;
      float rstd = rsqrtf(var + 1e-5f);
      size_t rowb = ((size_t)(b * 4096 + t0 + tl)) * 256;
      #pragma unroll
      for (int n = 0; n < 4; n++){
        float yv = (acc[m][n][r] - mu) * rstd * gj[n] + lj[n];
        yout[rowb + w * 64 + n * 16 + cc] = yv;
        jm[n] = fmaxf(jm[n], fabsf(yv));
      }
    }
  }
  #pragma unroll
  for (int n = 0; n < 4; n++){
    jm[n] = fmaxf(jm[n], __shfl_xor(jm[n], 16));
    jm[n] = fmaxf(jm[n], __shfl_xor(jm[n], 32));
  }
  if (g == 0){
    #pragma unroll
    for (int n = 0; n < 4; n++)
      atomicMax(&ymax[b * 256 + w * 64 + n * 16 + cc], __float_as_uint(jm[n]));
  }
}

// ---------------- final ratio ----------------
__global__ void k_ratio(const unsigned* __restrict__ ymax, const unsigned* __restrict__ xmax,
                        float* __restrict__ out){
  int i = blockIdx.x * 256 + threadIdx.x;
  if (i < 2048){
    float ym = __uint_as_float(ymax[i]);
    float xm = __uint_as_float(xmax[i]);
    out[8388608 + i] = ym / (xm + 1e-6f);
  }
}

extern "C" void kernel_launch(void* const* d_in, const int* in_sizes, int n_in,
                              void* d_out, int out_size, void* d_ws, size_t ws_size,
                              hipStream_t stream)
{
  const float* x    = (const float*)d_in[0];
  const float* Lr   = (const float*)d_in[1];
  const float* Li   = (const float*)d_in[2];
  const float* Pr   = (const float*)d_in[3];
  const float* Pi   = (const float*)d_in[4];
  const float* Qr   = (const float*)d_in[5];
  const float* Qi   = (const float*)d_in[6];
  const float* Br   = (const float*)d_in[7];
  const float* Bi   = (const float*)d_in[8];
  const float* Cr   = (const float*)d_in[9];
  const float* Ci   = (const float*)d_in[10];
  const float* stp  = (const float*)d_in[11];
  const float* Dp   = (const float*)d_in[12];
  const float* Wfc  = (const float*)d_in[13];
  const float* bfc  = (const float*)d_in[14];
  const float* lng  = (const float*)d_in[15];
  const float* lnb  = (const float*)d_in[16];

  char* ws = (char*)d_ws;
  float*    xT   = (float*)(ws);                                     // 32 MB
  float4*   Sab  = (float4*)(ws + ((size_t)32 << 20));               // ~8.4 MB (128*4097*16)
  cf*       A    = (cf*)(ws + ((size_t)41 << 20));                   // 8 MB (dead after k_kf)
  ushort*   y1h  = (ushort*)(ws + ((size_t)41 << 20));               // 16 MB (overlays A)
  ushort*   y1l  = (ushort*)(ws + ((size_t)57 << 20));               // 16 MB
  ushort*   Wh   = (ushort*)(ws + ((size_t)73 << 20));               // 128 KB
  ushort*   Wl   = (ushort*)(ws + ((size_t)73 << 20) + (128u << 10));
  unsigned* xmax = (unsigned*)(ws + ((size_t)73 << 20) + (256u << 10));
  unsigned* ymax = xmax + 2048;
  cf*       CBt  = (cf*)(ws + ((size_t)74 << 20));                   // 128 KB (64 n x 256 h)
  cf*       CPt  = (cf*)(ws + ((size_t)74 << 20) + (128u << 10));    // 128 KB

  k_wsplit<<<256, 256, 0, stream>>>(Wfc, Wh, Wl, xmax, ymax, Cr, Ci, Br, Bi, Pr, Pi, CBt, CPt);
  dim3 gt(64, 4, 8);
  k_transpose_x<<<gt, 256, 0, stream>>>(x, xT, xmax);
  k_cauchy<<<512, 256, 0, stream>>>(Lr, Li, Pr, Pi, Qr, Qi, Br, Bi, CBt, CPt, stp, A);
  k_kf<<<128, 1024, 65536, stream>>>(A, Sab);
  k_conv<<<1024, 256, 0, stream>>>(xT, Sab, Dp, y1h, y1l);
  k_gemm_ln<<<512, 256, 0, stream>>>(y1h, y1l, Wh, Wl, bfc, x, lng, lnb, (float*)d_out, ymax);
  k_ratio<<<8, 256, 0, stream>>>(ymax, xmax, (float*)d_out);
}